// Round 14
// baseline (205.616 us; speedup 1.0000x reference)
//
#include <hip/hip_runtime.h>
#include <hip/hip_bf16.h>
#include <stdint.h>
#include <stddef.h>

// E=8, B=16, T=512, DIN=256, D=256; M = B*T = 8192 rows per ensemble member.
// Stage1: u = x @ W_in[m], v=tanh(u0), f=sig(u1)*(1-rs)  -> scan1 -> v4
// Stage2: u = v4 @ W_mid[m], gates f,i,o,z               -> scan2 -> g = h*o
// Stage3: out = g @ W_out + b_out
//
// r14 = r11 structure with WIDE TILES: 128x256 (Breg[4][8]=128 VGPR, acc[4][4]).
// A-staging / ds_reads / barriers per tile unchanged; MFMA+epilogue per tile
// double; tile count halves -> amortizes the measured ~10-13k cy/tile fixed
// cost. vmcnt(16) at tile end keeps the 16 epilogue stores in flight.

typedef __bf16 bf16x8 __attribute__((ext_vector_type(8)));
typedef __bf16 bf16x4 __attribute__((ext_vector_type(4)));
typedef __bf16 bf16x2 __attribute__((ext_vector_type(2)));
typedef float  f32x4  __attribute__((ext_vector_type(4)));
typedef float  f32x2  __attribute__((ext_vector_type(2)));

#define E_ 8
#define M_ 8192
#define K_ 256

__device__ __forceinline__ float sigm_f(float x) {
    return __builtin_amdgcn_rcpf(1.0f + __expf(-x));
}
__device__ __forceinline__ float tanh_f(float x) {
    return 1.0f - 2.0f * __builtin_amdgcn_rcpf(1.0f + __expf(2.0f * x));
}

__device__ __forceinline__ void g2lds16(const void* g, void* l) {
    __builtin_amdgcn_global_load_lds((const __attribute__((address_space(1))) void*)g,
                                     (__attribute__((address_space(3))) void*)l, 16, 0, 0);
}

// DPP row_shr with 0-fill (bound_ctrl=1); rows of 16 lanes = our ln15 groups.
template <int D>
__device__ __forceinline__ float dppshr(float x) {
    return __builtin_bit_cast(float,
        __builtin_amdgcn_update_dpp(0, __builtin_bit_cast(int, x),
                                    0x110 | D, 0xF, 0xF, true));
}

// Inclusive Hillis scan of (A,B) over 16-lane rows, then exclusive prefix.
__device__ __forceinline__ void lane_scan(float& A, float& B, float& EA, float& EB, int ln15) {
    float As, Bs;
    Bs = dppshr<1>(B); As = dppshr<1>(A); B = __builtin_fmaf(A, Bs, B); A = (ln15 >= 1) ? A * As : A;
    Bs = dppshr<2>(B); As = dppshr<2>(A); B = __builtin_fmaf(A, Bs, B); A = (ln15 >= 2) ? A * As : A;
    Bs = dppshr<4>(B); As = dppshr<4>(A); B = __builtin_fmaf(A, Bs, B); A = (ln15 >= 4) ? A * As : A;
    Bs = dppshr<8>(B); As = dppshr<8>(A); B = __builtin_fmaf(A, Bs, B); A = (ln15 >= 8) ? A * As : A;
    EA = dppshr<1>(A); EA = (ln15 >= 1) ? EA : 1.0f;
    EB = dppshr<1>(B);
}

// ---------------- convert x to bf16 ----------------
__global__ __launch_bounds__(256) void convx_k(const float* __restrict__ x, __bf16* __restrict__ xb) {
    int i = blockIdx.x * 256 + threadIdx.x;
    float4 v = ((const float4*)x)[i];
    bf16x4 o;
    o[0] = (__bf16)v.x; o[1] = (__bf16)v.y; o[2] = (__bf16)v.z; o[3] = (__bf16)v.w;
    ((bf16x4*)xb)[i] = o;
}

// ---------------- transpose+convert weights ----------------
// src [GE][K][D] f32 -> dst [E][NG*256][K] bf16; row' = ilv ? d*NG+g : g*256+d
__global__ __launch_bounds__(256) void transw_k(const float* __restrict__ src, __bf16* __restrict__ dst,
                                                int NG, int ilv) {
    int ge = blockIdx.z;
    int g = ge >> 3, e = ge & 7;
    int k0 = blockIdx.x * 64, d0 = blockIdx.y * 64;
    __shared__ float tile[64][65];
    int t = threadIdx.x;
#pragma unroll
    for (int j = 0; j < 16; ++j) {
        int lin = j * 256 + t;
        int r = lin >> 6, c = lin & 63;
        tile[r][c] = src[((size_t)(ge * 256 + k0 + r)) * 256 + d0 + c];
    }
    __syncthreads();
#pragma unroll
    for (int j = 0; j < 16; ++j) {
        int lin = j * 256 + t;
        int r = lin >> 6, c = lin & 63;     // r = d offset, c = k offset
        int d = d0 + r;
        int row = ilv ? (d * NG + g) : (g * 256 + d);
        dst[((size_t)(e * NG * 256 + row)) * K_ + k0 + c] = (__bf16)tile[c][r];
    }
}

// ---------------- persistent GEMM, wide 128x256 tiles, fused scan ----------------
// MODE 0: NG=2 ilv (q: v(d0),f(d0),v(d1),f(d1)); fused scan1 -> v4b bf16, hidout[:, :256]
// MODE 1: NG=4 ilv (q: f,i,o,z of one d);       fused scan2 -> G bf16, hidout[:, 256:]
// MODE 2: NG=1 plain: linear+bias -> f32 d_out
template <int MODE, int NG>
__global__ __launch_bounds__(512, 1) void gemm_k(const __bf16* __restrict__ A,
                                                 const __bf16* __restrict__ Wt,
                                                 const float* __restrict__ bias,
                                                 const float* __restrict__ rs,
                                                 __bf16* __restrict__ gout,
                                                 float* __restrict__ fout,
                                                 const float* __restrict__ hidden,
                                                 float* __restrict__ hidout) {
    constexpr int NT  = NG;              // n-panels of 256
    constexpr int NMT = 2 * NG;          // m-tiles per block (grid = 256)
    const int tid = threadIdx.x;
    const int bid = blockIdx.x;          // 256 blocks, bid&7 = e = XCD
    const int e  = bid & 7;
    const int rr = bid >> 3;             // 0..31
    const int nt = rr % NT;
    const int ms = rr / NT;              // 0..(32/NT)-1
    const int mt0 = ms * NMT;
    const int lane = tid & 63, wid = tid >> 6;
    const int wr = wid >> 2, wc = wid & 3;          // 2x4 wave grid: 64 rows x 64 cols
    const int ln15 = lane & 15, ln16 = lane >> 4;

    __shared__ __align__(16) __bf16 As[2][32768];   // 2 x (128 rows x 256 k) = 128 KB
    __shared__ float cAl[128], cBl[128];            // wr0 wave totals per d-slot
    __shared__ float chL[2][128];                   // running h per d-slot (tile-parity dbuf)

    // ---- B panel into registers: 4 j-tiles x 8 k-steps = 128 VGPR ----
    bf16x8 Breg[4][8];
    {
        const __bf16* bp = Wt + ((size_t)e * (NG * 256) + nt * 256 + wc * 64 + ln15) * K_ + ln16 * 8;
#pragma unroll
        for (int j = 0; j < 4; ++j)
#pragma unroll
            for (int s = 0; s < 8; ++s)
                Breg[j][s] = *(const bf16x8*)(bp + (size_t)j * 16 * K_ + s * 32);
    }
    // ---- bias preload (per-q gather honoring interleave) ----
    f32x4 bias_v[4];
#pragma unroll
    for (int j = 0; j < 4; ++j) {
        int n0 = nt * 256 + wc * 64 + j * 16 + (ln16 << 2);
        if constexpr (MODE == 0) {
#pragma unroll
            for (int q = 0; q < 4; ++q) {
                int n = n0 + q;
                bias_v[j][q] = bias[((n & 1) * E_ + e) * 256 + (n >> 1)];
            }
        } else if constexpr (MODE == 1) {
#pragma unroll
            for (int q = 0; q < 4; ++q) {
                int n = n0 + q;
                bias_v[j][q] = bias[((n & 3) * E_ + e) * 256 + (n >> 2)];
            }
        } else {
            bias_v[j] = *(const f32x4*)&bias[e * 256 + n0];
        }
    }

    // ---- staging: full contiguous rows; source pre-XOR'd with key=(row>>2)&7 ----
    const size_t Ae = ((size_t)e * M_ + (size_t)mt0 * 128) * K_;
    const int sr = tid >> 5, sr2 = sr >> 2;
    const int gg0 = (tid & 31) ^ sr2;
    const __bf16* sE = A + Ae + (size_t)sr * K_ + gg0 * 8;
    const __bf16* sO = A + Ae + (size_t)sr * K_ + (gg0 ^ 4) * 8;
    __bf16* const dbase0 = &As[0][tid * 8];
    __bf16* const dbase1 = &As[1][tid * 8];

    auto stage = [&](int tt, int buf) {
        __bf16* d = buf ? dbase1 : dbase0;
        const size_t toff = (size_t)tt * (128 * K_);
#pragma unroll
        for (int q = 0; q < 8; ++q)
            g2lds16(((q & 1) ? sO : sE) + toff + q * (16 * K_), d + q * 4096);
    };

    // ---- ds_read fragment bases: row = wr*64 + ln15*4 + i, granule ^ (ln15&7) ----
    const int rowb = (wr * 64 + ln15 * 4) * K_;
    const int gb = ln16 ^ (lane & 7);
    const int pe_off = rowb + gb * 8;
    const int po_off = rowb + (gb ^ 4) * 8;

    f32x4 acc[4][4] = {};

    auto compute = [&](int buf) {
        const __bf16* pe = &As[0][0] + buf * 32768 + pe_off;
        const __bf16* po = &As[0][0] + buf * 32768 + po_off;
#pragma unroll
        for (int s = 0; s < 8; ++s) {
            const __bf16* p = (s & 1) ? po : pe;
            bf16x8 af[4];
#pragma unroll
            for (int i = 0; i < 4; ++i)
                af[i] = *(const bf16x8*)(p + i * K_ + (s >> 1) * 64);
#pragma unroll
            for (int i = 0; i < 4; ++i)
#pragma unroll
                for (int j = 0; j < 4; ++j)
                    acc[i][j] = __builtin_amdgcn_mfma_f32_16x16x32_bf16(Breg[j][s], af[i], acc[i][j], 0, 0, 0);
        }
    };

    // ---- prologue ----
    stage(0, 0);
    asm volatile("s_waitcnt vmcnt(0)" ::: "memory");
    __builtin_amdgcn_s_barrier();
    __builtin_amdgcn_sched_barrier(0);

    int buf = 0;
    for (int t = 0; t < NMT; ++t) {
        const bool cs = ((t & 3) == 0);
        const int nrow = e * 16 + ((mt0 + t) >> 2);
        // ---- hoisted epilogue loads (before stage(t+1)) ----
        f32x4 rs4 = {};
        float hidv[8];
        if constexpr (MODE != 2) {
            const int mbh = (mt0 + t) * 128 + wr * 64 + ln15 * 4;
            rs4 = *(const f32x4*)&rs[mbh];
            if constexpr (MODE == 1) {
#pragma unroll
                for (int j = 0; j < 4; ++j)
                    hidv[j] = hidden[nrow * 512 + 256 + (nt * 64 + wc * 16 + j * 4 + ln16)];
            } else {
#pragma unroll
                for (int j = 0; j < 4; ++j) {
                    f32x2 hv = *(const f32x2*)&hidden[nrow * 512 + (nt * 128 + wc * 32 + j * 8 + ln16 * 2)];
                    hidv[j * 2] = hv[0]; hidv[j * 2 + 1] = hv[1];
                }
            }
            __builtin_amdgcn_sched_barrier(0);
        }

        if (t + 1 < NMT) stage(t + 1, buf ^ 1);
        compute(buf);

        const int mt = mt0 + t;
        const int mb = mt * 128 + wr * 64 + ln15 * 4;   // first m of this thread

        if constexpr (MODE == 2) {
#pragma unroll
            for (int j = 0; j < 4; ++j) {
                const int n0 = nt * 256 + wc * 64 + j * 16 + (ln16 << 2);
#pragma unroll
                for (int i = 0; i < 4; ++i) {
                    f32x4 o = acc[i][j] + bias_v[j];
                    *(f32x4*)&fout[((size_t)e * M_ + mb + i) * 256 + n0] = o;
                    acc[i][j] = f32x4{};
                }
            }
        } else {
            f32x4 rsv;
#pragma unroll
            for (int q = 0; q < 4; ++q) rsv[q] = 1.0f - rs4[q];

            if constexpr (MODE == 1) {
                float PA[4][4], PB[4][4], Ov[4][4], LA[4], LB[4], EA[4], EB[4];
#pragma unroll
                for (int j = 0; j < 4; ++j) {
#pragma unroll
                    for (int i = 0; i < 4; ++i) {
                        float f  = sigm_f(acc[i][j][0] + bias_v[j][0]) * rsv[i];
                        float iv = sigm_f(acc[i][j][1] + bias_v[j][1]);
                        float o  = sigm_f(acc[i][j][2] + bias_v[j][2]);
                        float z  = tanh_f(acc[i][j][3] + bias_v[j][3]);
                        float b  = (1.0f - f) * iv * z;
                        Ov[j][i] = o;
                        if (i == 0) { PA[j][0] = f; PB[j][0] = b; }
                        else { PB[j][i] = __builtin_fmaf(f, PB[j][i - 1], b); PA[j][i] = PA[j][i - 1] * f; }
                        acc[i][j] = f32x4{};
                    }
                    LA[j] = PA[j][3]; LB[j] = PB[j][3];
                    lane_scan(LA[j], LB[j], EA[j], EB[j], ln15);
                }
                if (wr == 0 && ln15 == 15) {
#pragma unroll
                    for (int j = 0; j < 4; ++j) {
                        int sl = wc * 16 + j * 4 + ln16;
                        cAl[sl] = LA[j]; cBl[sl] = LB[j];
                    }
                }
                asm volatile("s_waitcnt lgkmcnt(0)" ::: "memory");
                __builtin_amdgcn_s_barrier();
#pragma unroll
                for (int j = 0; j < 4; ++j) {
                    const int sl = wc * 16 + j * 4 + ln16;
                    const int d = nt * 64 + sl;
                    float hp = cs ? hidv[j] : chL[t & 1][sl];
                    float hs = wr ? __builtin_fmaf(cAl[sl], hp, cBl[sl]) : hp;
                    float h0 = __builtin_fmaf(EA[j], hs, EB[j]);
#pragma unroll
                    for (int i = 0; i < 4; ++i) {
                        float h = __builtin_fmaf(PA[j][i], h0, PB[j][i]);
                        gout[((size_t)e * M_ + mb + i) * 256 + d] = (__bf16)(h * Ov[j][i]);
                    }
                    if (wr == 1 && ln15 == 15) {
                        float he = __builtin_fmaf(LA[j], hs, LB[j]);
                        chL[(t + 1) & 1][sl] = he;
                        if ((t & 3) == 3)
                            hidout[nrow * 512 + 256 + d] = he;
                    }
                }
            } else {
                // MODE 0: q = v(d0), f(d0), v(d1), f(d1): two scan streams per j
                float PA[4][2][4], PB[4][2][4], LA[4][2], LB[4][2], EA[4][2], EB[4][2];
#pragma unroll
                for (int j = 0; j < 4; ++j) {
#pragma unroll
                    for (int dq = 0; dq < 2; ++dq) {
#pragma unroll
                        for (int i = 0; i < 4; ++i) {
                            float uv = acc[i][j][dq * 2 + 0] + bias_v[j][dq * 2 + 0];
                            float uf = acc[i][j][dq * 2 + 1] + bias_v[j][dq * 2 + 1];
                            float f = sigm_f(uf) * rsv[i];
                            float b = (1.0f - f) * tanh_f(uv);
                            if (i == 0) { PA[j][dq][0] = f; PB[j][dq][0] = b; }
                            else { PB[j][dq][i] = __builtin_fmaf(f, PB[j][dq][i - 1], b);
                                   PA[j][dq][i] = PA[j][dq][i - 1] * f; }
                        }
                        LA[j][dq] = PA[j][dq][3]; LB[j][dq] = PB[j][dq][3];
                        lane_scan(LA[j][dq], LB[j][dq], EA[j][dq], EB[j][dq], ln15);
                    }
#pragma unroll
                    for (int i = 0; i < 4; ++i) acc[i][j] = f32x4{};
                }
                if (wr == 0 && ln15 == 15) {
#pragma unroll
                    for (int j = 0; j < 4; ++j)
#pragma unroll
                        for (int dq = 0; dq < 2; ++dq) {
                            int sl = wc * 32 + j * 8 + ln16 * 2 + dq;
                            cAl[sl] = LA[j][dq]; cBl[sl] = LB[j][dq];
                        }
                }
                asm volatile("s_waitcnt lgkmcnt(0)" ::: "memory");
                __builtin_amdgcn_s_barrier();
#pragma unroll
                for (int j = 0; j < 4; ++j) {
                    const int D0 = nt * 128 + wc * 32 + j * 8 + ln16 * 2;
                    float h0q[2];
#pragma unroll
                    for (int dq = 0; dq < 2; ++dq) {
                        const int sl = wc * 32 + j * 8 + ln16 * 2 + dq;
                        float hp = cs ? hidv[j * 2 + dq] : chL[t & 1][sl];
                        float hs = wr ? __builtin_fmaf(cAl[sl], hp, cBl[sl]) : hp;
                        h0q[dq] = __builtin_fmaf(EA[j][dq], hs, EB[j][dq]);
                        if (wr == 1 && ln15 == 15) {
                            float he = __builtin_fmaf(LA[j][dq], hs, LB[j][dq]);
                            chL[(t + 1) & 1][sl] = he;
                            if ((t & 3) == 3)
                                hidout[nrow * 512 + D0 + dq] = he;
                        }
                    }
#pragma unroll
                    for (int i = 0; i < 4; ++i) {
                        float ha = __builtin_fmaf(PA[j][0][i], h0q[0], PB[j][0][i]);
                        float hb = __builtin_fmaf(PA[j][1][i], h0q[1], PB[j][1][i]);
                        bf16x2 pk; pk[0] = (__bf16)ha; pk[1] = (__bf16)hb;
                        *(unsigned int*)&gout[((size_t)e * M_ + mb + i) * 256 + D0] =
                            __builtin_bit_cast(unsigned int, pk);
                    }
                }
            }
        }
        // stage(t+1) retired (stores are the newest 16, stay in flight)
        asm volatile("s_waitcnt vmcnt(16) lgkmcnt(0)" ::: "memory");
        __builtin_amdgcn_s_barrier();
        __builtin_amdgcn_sched_barrier(0);
        buf ^= 1;
    }
}

extern "C" void kernel_launch(void* const* d_in, const int* in_sizes, int n_in,
                              void* d_out, int out_size, void* d_ws, size_t ws_size,
                              hipStream_t stream) {
    const float* x      = (const float*)d_in[0];
    const float* hidden = (const float*)d_in[1];
    const float* rs     = (const float*)d_in[2];
    const float* W_in   = (const float*)d_in[3];
    const float* b_in   = (const float*)d_in[4];
    const float* W_mid  = (const float*)d_in[5];
    const float* b_mid  = (const float*)d_in[6];
    const float* W_out  = (const float*)d_in[7];
    const float* b_out  = (const float*)d_in[8];
    float* out = (float*)d_out;

    char* ws = (char*)d_ws;
    const size_t MiB = (size_t)1 << 20;
    __bf16* Wt1 = (__bf16*)(ws + 0);               // 2 MiB  (ilv d*2+g)
    __bf16* Wt2 = (__bf16*)(ws + 2 * MiB);         // 4 MiB  (ilv d*4+g)
    __bf16* Wt3 = (__bf16*)(ws + 6 * MiB);         // 1 MiB  (plain)
    __bf16* v4b = (__bf16*)(ws + 8 * MiB);         // 32 MiB scan1 output
    __bf16* xb  = (__bf16*)(ws + 40 * MiB);        // 32 MiB
    __bf16* G   = (__bf16*)(ws + 72 * MiB);        // 32 MiB scan2 output

    float* hidout = out + (size_t)E_ * M_ * 256;

    convx_k<<<16384, 256, 0, stream>>>(x, xb);
    transw_k<<<dim3(4, 4, 16), 256, 0, stream>>>(W_in, Wt1, 2, 1);
    transw_k<<<dim3(4, 4, 32), 256, 0, stream>>>(W_mid, Wt2, 4, 1);
    transw_k<<<dim3(4, 4, 8), 256, 0, stream>>>(W_out, Wt3, 1, 0);

    gemm_k<0, 2><<<256, 512, 0, stream>>>(xb, Wt1, b_in, rs, v4b, nullptr, hidden, hidout);
    gemm_k<1, 4><<<256, 512, 0, stream>>>(v4b, Wt2, b_mid, rs, G, nullptr, hidden, hidout);
    gemm_k<2, 1><<<256, 512, 0, stream>>>(G, Wt3, b_out, nullptr, nullptr, out, nullptr, nullptr);
}

// Round 15
// 162.269 us; speedup vs baseline: 1.2671x; 1.2671x over previous
//
#include <hip/hip_runtime.h>
#include <hip/hip_bf16.h>
#include <stdint.h>
#include <stddef.h>

// E=8, B=16, T=512, DIN=256, D=256; M = B*T = 8192 rows per ensemble member.
// Stage1: u = x @ W_in[m], v=tanh(u0), f=sig(u1)*(1-rs)  -> scan1 -> v4
// Stage2: u = v4 @ W_mid[m], gates f,i,o,z               -> scan2 -> g = h*o
// Stage3: out = g @ W_out + b_out
//
// r15 = r13 (deferred-epilogue fused-scan GEMM, best 170.9us) +
//  (a) convx_k ELIMINATED: gemm1 (MODE0) reg-stages x directly from f32
//      (16x global_load_dwordx4 issued at tile top, cvt+ds_write_b128 after
//      the tile-end vmcnt; XOR swizzle applied on the ds_write address ->
//      LDS image identical to before, downstream math bit-identical).
//      Saves 96MB conversion kernel + 64MB xb round-trip.
//  (b) 3 transw launches merged into one (block-range dispatch).
// gemm2 (MODE1) / gemm3 (MODE2) unchanged from r13.

typedef __bf16 bf16x8 __attribute__((ext_vector_type(8)));
typedef __bf16 bf16x4 __attribute__((ext_vector_type(4)));
typedef __bf16 bf16x2 __attribute__((ext_vector_type(2)));
typedef float  f32x4  __attribute__((ext_vector_type(4)));
typedef float  f32x2  __attribute__((ext_vector_type(2)));

#define E_ 8
#define M_ 8192
#define K_ 256

__device__ __forceinline__ float sigm_f(float x) {
    return __builtin_amdgcn_rcpf(1.0f + __expf(-x));
}
__device__ __forceinline__ float tanh_f(float x) {
    return 1.0f - 2.0f * __builtin_amdgcn_rcpf(1.0f + __expf(2.0f * x));
}

__device__ __forceinline__ void g2lds16(const void* g, void* l) {
    __builtin_amdgcn_global_load_lds((const __attribute__((address_space(1))) void*)g,
                                     (__attribute__((address_space(3))) void*)l, 16, 0, 0);
}

// DPP row_shr with 0-fill (bound_ctrl=1); rows of 16 lanes = our ln15 groups.
template <int D>
__device__ __forceinline__ float dppshr(float x) {
    return __builtin_bit_cast(float,
        __builtin_amdgcn_update_dpp(0, __builtin_bit_cast(int, x),
                                    0x110 | D, 0xF, 0xF, true));
}

// Inclusive Hillis scan of (A,B) over 16-lane rows, then exclusive prefix.
__device__ __forceinline__ void lane_scan(float& A, float& B, float& EA, float& EB, int ln15) {
    float As, Bs;
    Bs = dppshr<1>(B); As = dppshr<1>(A); B = __builtin_fmaf(A, Bs, B); A = (ln15 >= 1) ? A * As : A;
    Bs = dppshr<2>(B); As = dppshr<2>(A); B = __builtin_fmaf(A, Bs, B); A = (ln15 >= 2) ? A * As : A;
    Bs = dppshr<4>(B); As = dppshr<4>(A); B = __builtin_fmaf(A, Bs, B); A = (ln15 >= 4) ? A * As : A;
    Bs = dppshr<8>(B); As = dppshr<8>(A); B = __builtin_fmaf(A, Bs, B); A = (ln15 >= 8) ? A * As : A;
    EA = dppshr<1>(A); EA = (ln15 >= 1) ? EA : 1.0f;
    EB = dppshr<1>(B);
}

// ---------------- merged transpose+convert for all three weight sets ----------------
// src [GE][K][D] f32 -> dst [E][NG*256][K] bf16; row' = ilv ? d*NG+g : g*256+d
__global__ __launch_bounds__(256) void transw_all(const float* __restrict__ W_in,
                                                  const float* __restrict__ W_mid,
                                                  const float* __restrict__ W_out,
                                                  __bf16* __restrict__ Wt1,
                                                  __bf16* __restrict__ Wt2,
                                                  __bf16* __restrict__ Wt3) {
    int z = blockIdx.z;
    const float* src; __bf16* dst; int NG, ilv, ge;
    if (z < 16)      { src = W_in;  dst = Wt1; NG = 2; ilv = 1; ge = z; }
    else if (z < 48) { src = W_mid; dst = Wt2; NG = 4; ilv = 1; ge = z - 16; }
    else             { src = W_out; dst = Wt3; NG = 1; ilv = 0; ge = z - 48; }
    int g = ge >> 3, e = ge & 7;
    int k0 = blockIdx.x * 64, d0 = blockIdx.y * 64;
    __shared__ float tile[64][65];
    int t = threadIdx.x;
#pragma unroll
    for (int j = 0; j < 16; ++j) {
        int lin = j * 256 + t;
        int r = lin >> 6, c = lin & 63;
        tile[r][c] = src[((size_t)(ge * 256 + k0 + r)) * 256 + d0 + c];
    }
    __syncthreads();
#pragma unroll
    for (int j = 0; j < 16; ++j) {
        int lin = j * 256 + t;
        int r = lin >> 6, c = lin & 63;     // r = d offset, c = k offset
        int d = d0 + r;
        int row = ilv ? (d * NG + g) : (g * 256 + d);
        dst[((size_t)(e * NG * 256 + row)) * K_ + k0 + c] = (__bf16)tile[c][r];
    }
}

// ---------------- persistent GEMM with fused scan, deferred epilogue ----------------
// MODE 0: NG=2 ilv (q: v(d0),f(d0),v(d1),f(d1)); A = Af (f32, reg-staged+cvt);
//         fused scan1 -> v4b bf16, hidout[:, :256]
// MODE 1: NG=4 ilv (q: f,i,o,z of one d); A bf16 via global_load_lds;
//         fused scan2 -> G bf16, hidout[:, 256:]
// MODE 2: NG=1 plain: linear+bias -> f32 d_out
template <int MODE, int NG>
__global__ __launch_bounds__(512, 1) void gemm_k(const __bf16* __restrict__ A,
                                                 const float* __restrict__ Af,
                                                 const __bf16* __restrict__ Wt,
                                                 const float* __restrict__ bias,
                                                 const float* __restrict__ rs,
                                                 __bf16* __restrict__ gout,
                                                 float* __restrict__ fout,
                                                 const float* __restrict__ hidden,
                                                 float* __restrict__ hidout) {
    constexpr int NT  = NG * 2;          // n-panels of 128
    constexpr int NMT = 2 * NT;          // m-tiles per block (grid = 256)
    const int tid = threadIdx.x;
    const int bid = blockIdx.x;          // 256 blocks, bid&7 = e = XCD
    const int e  = bid & 7;
    const int rr = bid >> 3;             // 0..31
    const int nt = rr & (NT - 1);
    const int ms = rr / NT;
    const int mt0 = ms * NMT;
    const int lane = tid & 63, wid = tid >> 6;
    const int wr = wid >> 2, wc = wid & 3;          // 2x4 wave grid
    const int ln15 = lane & 15, ln16 = lane >> 4;

    __shared__ __align__(16) __bf16 As[2][32768];   // 2 x (128 rows x 256 k) = 128 KB
    __shared__ float cAl[64], cBl[64];              // wr0 wave totals per d-slot
    __shared__ float chL[2][64];                    // running h per d-slot (tile-parity dbuf)

    // ---- B panel into registers ----
    bf16x8 Breg[2][8];
    {
        const __bf16* bp = Wt + ((size_t)e * (NG * 256) + nt * 128 + wc * 32 + ln15) * K_ + ln16 * 8;
#pragma unroll
        for (int j = 0; j < 2; ++j)
#pragma unroll
            for (int s = 0; s < 8; ++s)
                Breg[j][s] = *(const bf16x8*)(bp + (size_t)j * 16 * K_ + s * 32);
    }
    // ---- bias preload (per-q gather honoring interleave) ----
    f32x4 bias_v[2];
#pragma unroll
    for (int j = 0; j < 2; ++j) {
        int n0 = nt * 128 + wc * 32 + j * 16 + (ln16 << 2);
        if constexpr (MODE == 0) {
#pragma unroll
            for (int q = 0; q < 4; ++q) {
                int n = n0 + q;
                bias_v[j][q] = bias[((n & 1) * E_ + e) * 256 + (n >> 1)];
            }
        } else if constexpr (MODE == 1) {
#pragma unroll
            for (int q = 0; q < 4; ++q) {
                int n = n0 + q;
                bias_v[j][q] = bias[((n & 3) * E_ + e) * 256 + (n >> 2)];
            }
        } else {
            bias_v[j] = *(const f32x4*)&bias[e * 256 + n0];
        }
    }

    // ---- staging geometry: full contiguous rows; source pre-XOR'd key=(row>>2)&7 ----
    const int sr = tid >> 5, sr2 = sr >> 2;
    const int gg0 = (tid & 31) ^ sr2;
    const size_t Aoff = ((size_t)e * M_ + (size_t)mt0 * 128) * K_;
    const __bf16* sE = nullptr; const __bf16* sO = nullptr;
    const float*  sEf = nullptr; const float* sOf = nullptr;
    if constexpr (MODE == 0) {
        sEf = Af + Aoff + (size_t)sr * K_ + gg0 * 8;
        sOf = Af + Aoff + (size_t)sr * K_ + (gg0 ^ 4) * 8;
    } else {
        sE = A + Aoff + (size_t)sr * K_ + gg0 * 8;
        sO = A + Aoff + (size_t)sr * K_ + (gg0 ^ 4) * 8;
    }
    __bf16* const dbase0 = &As[0][tid * 8];
    __bf16* const dbase1 = &As[1][tid * 8];

    auto stage = [&](int tt, int buf) {              // MODE!=0: global_load_lds path
        __bf16* d = buf ? dbase1 : dbase0;
        const size_t toff = (size_t)tt * (128 * K_);
#pragma unroll
        for (int q = 0; q < 8; ++q)
            g2lds16(((q & 1) ? sO : sE) + toff + q * (16 * K_), d + q * 4096);
    };

    f32x4 tA[8], tB[8];                              // MODE0 reg-staging buffers
    auto loadx = [&](int tt) {
        const size_t toff = (size_t)tt * (128 * K_);
#pragma unroll
        for (int q = 0; q < 8; ++q) {
            const float* s = ((q & 1) ? sOf : sEf) + toff + q * (16 * K_);
            tA[q] = *(const f32x4*)s;
            tB[q] = *(const f32x4*)(s + 4);
        }
    };
    auto writex = [&](int buf) {
        __bf16* d = buf ? dbase1 : dbase0;
#pragma unroll
        for (int q = 0; q < 8; ++q) {
            bf16x8 w;
#pragma unroll
            for (int k = 0; k < 4; ++k) { w[k] = (__bf16)tA[q][k]; w[4 + k] = (__bf16)tB[q][k]; }
            *(bf16x8*)(d + q * 4096) = w;
        }
    };

    // ---- ds_read fragment bases: row = wr*64 + ln15*4 + i, granule ^ (ln15&7) ----
    const int rowb = (wr * 64 + ln15 * 4) * K_;
    const int gb = ln16 ^ (lane & 7);
    const int pe_off = rowb + gb * 8;
    const int po_off = rowb + (gb ^ 4) * 8;

    auto compute = [&](f32x4 (&acc)[4][2], int buf) {
        const __bf16* pe = &As[0][0] + buf * 32768 + pe_off;
        const __bf16* po = &As[0][0] + buf * 32768 + po_off;
#pragma unroll
        for (int s = 0; s < 8; ++s) {
            const __bf16* p = (s & 1) ? po : pe;
            bf16x8 af[4];
#pragma unroll
            for (int i = 0; i < 4; ++i)
                af[i] = *(const bf16x8*)(p + i * K_ + (s >> 1) * 64);
#pragma unroll
            for (int i = 0; i < 4; ++i)
#pragma unroll
                for (int j = 0; j < 2; ++j)
                    acc[i][j] = __builtin_amdgcn_mfma_f32_16x16x32_bf16(Breg[j][s], af[i], acc[i][j], 0, 0, 0);
        }
    };

    if constexpr (MODE == 2) {
        // ---- r13-identical MODE2 loop ----
        stage(0, 0);
        asm volatile("s_waitcnt vmcnt(0)" ::: "memory");
        __builtin_amdgcn_s_barrier();
        __builtin_amdgcn_sched_barrier(0);
        f32x4 acc[4][2] = {};
        int buf = 0;
        for (int t = 0; t < NMT; ++t) {
            if (t + 1 < NMT) stage(t + 1, buf ^ 1);
            compute(acc, buf);
            const int mb = (mt0 + t) * 128 + wr * 64 + ln15 * 4;
#pragma unroll
            for (int j = 0; j < 2; ++j) {
                const int n0 = nt * 128 + wc * 32 + j * 16 + (ln16 << 2);
#pragma unroll
                for (int i = 0; i < 4; ++i) {
                    f32x4 o = acc[i][j] + bias_v[j];
                    *(f32x4*)&fout[((size_t)e * M_ + mb + i) * 256 + n0] = o;
                    acc[i][j] = f32x4{};
                }
            }
            asm volatile("s_waitcnt vmcnt(8) lgkmcnt(0)" ::: "memory");
            __builtin_amdgcn_s_barrier();
            __builtin_amdgcn_sched_barrier(0);
            buf ^= 1;
        }
        return;
    } else {
        // ---- deferred-epilogue loop ----
        auto do_epi = [&](f32x4 (&acc)[4][2], int tp, const f32x4& rs4p, const float* hidvp) {
            const bool cs = ((tp & 3) == 0);
            const int c = tp >> 2;
            const int mb = (mt0 + tp) * 128 + wr * 64 + ln15 * 4;
            f32x4 rsv;
#pragma unroll
            for (int q = 0; q < 4; ++q) rsv[q] = 1.0f - rs4p[q];

            if constexpr (MODE == 1) {
                float PA[2][4], PB[2][4], Ov[2][4], LA[2], LB[2], EA[2], EB[2];
#pragma unroll
                for (int j = 0; j < 2; ++j) {
#pragma unroll
                    for (int i = 0; i < 4; ++i) {
                        float f  = sigm_f(acc[i][j][0] + bias_v[j][0]) * rsv[i];
                        float iv = sigm_f(acc[i][j][1] + bias_v[j][1]);
                        float o  = sigm_f(acc[i][j][2] + bias_v[j][2]);
                        float z  = tanh_f(acc[i][j][3] + bias_v[j][3]);
                        float b  = (1.0f - f) * iv * z;
                        Ov[j][i] = o;
                        if (i == 0) { PA[j][0] = f; PB[j][0] = b; }
                        else { PB[j][i] = __builtin_fmaf(f, PB[j][i - 1], b); PA[j][i] = PA[j][i - 1] * f; }
                        acc[i][j] = f32x4{};
                    }
                    LA[j] = PA[j][3]; LB[j] = PB[j][3];
                    lane_scan(LA[j], LB[j], EA[j], EB[j], ln15);
                }
                if (wr == 0 && ln15 == 15) {
#pragma unroll
                    for (int j = 0; j < 2; ++j) {
                        int sl = wc * 8 + j * 4 + ln16;
                        cAl[sl] = LA[j]; cBl[sl] = LB[j];
                    }
                }
                asm volatile("s_waitcnt lgkmcnt(0)" ::: "memory");
                __builtin_amdgcn_s_barrier();
#pragma unroll
                for (int j = 0; j < 2; ++j) {
                    const int sl = wc * 8 + j * 4 + ln16;
                    const int d = nt * 32 + wc * 8 + j * 4 + ln16;
                    float hp = cs ? hidvp[j] : chL[tp & 1][sl];
                    float hs = wr ? __builtin_fmaf(cAl[sl], hp, cBl[sl]) : hp;
                    float h0 = __builtin_fmaf(EA[j], hs, EB[j]);
#pragma unroll
                    for (int i = 0; i < 4; ++i) {
                        float h = __builtin_fmaf(PA[j][i], h0, PB[j][i]);
                        gout[((size_t)e * M_ + mb + i) * 256 + d] = (__bf16)(h * Ov[j][i]);
                    }
                    if (wr == 1 && ln15 == 15) {
                        float he = __builtin_fmaf(LA[j], hs, LB[j]);
                        chL[(tp + 1) & 1][sl] = he;
                        if ((tp & 3) == 3)
                            hidout[(e * 16 + ms * 4 + c) * 512 + 256 + d] = he;
                    }
                }
            } else {
                // MODE 0: q = v(d0), f(d0), v(d1), f(d1): two scan streams per j
                float PA[2][2][4], PB[2][2][4], LA[2][2], LB[2][2], EA[2][2], EB[2][2];
#pragma unroll
                for (int j = 0; j < 2; ++j) {
#pragma unroll
                    for (int dq = 0; dq < 2; ++dq) {
#pragma unroll
                        for (int i = 0; i < 4; ++i) {
                            float uv = acc[i][j][dq * 2 + 0] + bias_v[j][dq * 2 + 0];
                            float uf = acc[i][j][dq * 2 + 1] + bias_v[j][dq * 2 + 1];
                            float f = sigm_f(uf) * rsv[i];
                            float b = (1.0f - f) * tanh_f(uv);
                            if (i == 0) { PA[j][dq][0] = f; PB[j][dq][0] = b; }
                            else { PB[j][dq][i] = __builtin_fmaf(f, PB[j][dq][i - 1], b);
                                   PA[j][dq][i] = PA[j][dq][i - 1] * f; }
                        }
                        LA[j][dq] = PA[j][dq][3]; LB[j][dq] = PB[j][dq][3];
                        lane_scan(LA[j][dq], LB[j][dq], EA[j][dq], EB[j][dq], ln15);
                    }
#pragma unroll
                    for (int i = 0; i < 4; ++i) acc[i][j] = f32x4{};
                }
                if (wr == 0 && ln15 == 15) {
#pragma unroll
                    for (int j = 0; j < 2; ++j)
#pragma unroll
                        for (int dq = 0; dq < 2; ++dq) {
                            int sl = wc * 16 + j * 8 + ln16 * 2 + dq;
                            cAl[sl] = LA[j][dq]; cBl[sl] = LB[j][dq];
                        }
                }
                asm volatile("s_waitcnt lgkmcnt(0)" ::: "memory");
                __builtin_amdgcn_s_barrier();
#pragma unroll
                for (int j = 0; j < 2; ++j) {
                    const int D0 = nt * 64 + wc * 16 + j * 8 + ln16 * 2;
                    float h0q[2];
#pragma unroll
                    for (int dq = 0; dq < 2; ++dq) {
                        const int sl = wc * 16 + j * 8 + ln16 * 2 + dq;
                        float hp = cs ? hidvp[j * 2 + dq] : chL[tp & 1][sl];
                        float hs = wr ? __builtin_fmaf(cAl[sl], hp, cBl[sl]) : hp;
                        h0q[dq] = __builtin_fmaf(EA[j][dq], hs, EB[j][dq]);
                        if (wr == 1 && ln15 == 15) {
                            float he = __builtin_fmaf(LA[j][dq], hs, LB[j][dq]);
                            chL[(tp + 1) & 1][sl] = he;
                            if ((tp & 3) == 3)
                                hidout[(e * 16 + ms * 2 + c) * 512 + D0 + dq] = he;
                        }
                    }
#pragma unroll
                    for (int i = 0; i < 4; ++i) {
                        float ha = __builtin_fmaf(PA[j][0][i], h0q[0], PB[j][0][i]);
                        float hb = __builtin_fmaf(PA[j][1][i], h0q[1], PB[j][1][i]);
                        bf16x2 pk; pk[0] = (__bf16)ha; pk[1] = (__bf16)hb;
                        *(unsigned int*)&gout[((size_t)e * M_ + mb + i) * 256 + D0] =
                            __builtin_bit_cast(unsigned int, pk);
                    }
                }
            }
        };

        // ---- prologue ----
        if constexpr (MODE == 0) {
            loadx(0);
            asm volatile("s_waitcnt vmcnt(0)" ::: "memory");
            writex(0);
            asm volatile("s_waitcnt lgkmcnt(0)" ::: "memory");
        } else {
            stage(0, 0);
            asm volatile("s_waitcnt vmcnt(0)" ::: "memory");
        }
        __builtin_amdgcn_s_barrier();
        __builtin_amdgcn_sched_barrier(0);

        f32x4 accA[4][2] = {}, accB[4][2] = {};
        f32x4 rs4_p = {};
        float hidv_p[4] = {0.f, 0.f, 0.f, 0.f};
        int buf = 0;

        auto iter = [&](int t, f32x4 (&accC)[4][2], f32x4 (&accP)[4][2]) {
            const int c = t >> 2;
            // ---- hoisted loads for tile t (consumed by epilogue at iter t+1) ----
            f32x4 rs4_n;
            float hidv_n[4] = {0.f, 0.f, 0.f, 0.f};
            {
                const int mbh = (mt0 + t) * 128 + wr * 64 + ln15 * 4;
                rs4_n = *(const f32x4*)&rs[mbh];
                if constexpr (MODE == 1) {
                    const int nrow = e * 16 + ms * 4 + c;
                    hidv_n[0] = hidden[nrow * 512 + 256 + (nt * 32 + wc * 8 + 0 + ln16)];
                    hidv_n[1] = hidden[nrow * 512 + 256 + (nt * 32 + wc * 8 + 4 + ln16)];
                } else {
                    const int nrow = e * 16 + ms * 2 + c;
                    f32x2 ha = *(const f32x2*)&hidden[nrow * 512 + (nt * 64 + wc * 16 + 0 + ln16 * 2)];
                    f32x2 hb = *(const f32x2*)&hidden[nrow * 512 + (nt * 64 + wc * 16 + 8 + ln16 * 2)];
                    hidv_n[0] = ha[0]; hidv_n[1] = ha[1]; hidv_n[2] = hb[0]; hidv_n[3] = hb[1];
                }
                __builtin_amdgcn_sched_barrier(0);
            }
            if constexpr (MODE == 0) {
                if (t + 1 < NMT) loadx(t + 1);
                __builtin_amdgcn_sched_barrier(0);
            } else {
                if (t + 1 < NMT) stage(t + 1, buf ^ 1);
            }
            compute(accC, buf);
            if (t > 0) do_epi(accP, t - 1, rs4_p, hidv_p);
            if (t == 0) {
                asm volatile("s_waitcnt vmcnt(0)" ::: "memory");
            } else {
                asm volatile("s_waitcnt vmcnt(8)" ::: "memory");
            }
            if constexpr (MODE == 0) {
                if (t + 1 < NMT) writex(buf ^ 1);
            }
            asm volatile("s_waitcnt lgkmcnt(0)" ::: "memory");
            __builtin_amdgcn_s_barrier();
            __builtin_amdgcn_sched_barrier(0);
            buf ^= 1;
            rs4_p = rs4_n;
#pragma unroll
            for (int q = 0; q < 4; ++q) hidv_p[q] = hidv_n[q];
        };

#pragma unroll 1
        for (int t2 = 0; t2 < NMT; t2 += 2) {
            iter(t2, accA, accB);
            iter(t2 + 1, accB, accA);
        }
        do_epi(accB, NMT - 1, rs4_p, hidv_p);
    }
}

extern "C" void kernel_launch(void* const* d_in, const int* in_sizes, int n_in,
                              void* d_out, int out_size, void* d_ws, size_t ws_size,
                              hipStream_t stream) {
    const float* x      = (const float*)d_in[0];
    const float* hidden = (const float*)d_in[1];
    const float* rs     = (const float*)d_in[2];
    const float* W_in   = (const float*)d_in[3];
    const float* b_in   = (const float*)d_in[4];
    const float* W_mid  = (const float*)d_in[5];
    const float* b_mid  = (const float*)d_in[6];
    const float* W_out  = (const float*)d_in[7];
    const float* b_out  = (const float*)d_in[8];
    float* out = (float*)d_out;

    char* ws = (char*)d_ws;
    const size_t MiB = (size_t)1 << 20;
    __bf16* Wt1 = (__bf16*)(ws + 0);               // 2 MiB  (ilv d*2+g)
    __bf16* Wt2 = (__bf16*)(ws + 2 * MiB);         // 4 MiB  (ilv d*4+g)
    __bf16* Wt3 = (__bf16*)(ws + 6 * MiB);         // 1 MiB  (plain)
    __bf16* v4b = (__bf16*)(ws + 8 * MiB);         // 32 MiB scan1 output
    __bf16* G   = (__bf16*)(ws + 72 * MiB);        // 32 MiB scan2 output

    float* hidout = out + (size_t)E_ * M_ * 256;

    transw_all<<<dim3(4, 4, 56), 256, 0, stream>>>(W_in, W_mid, W_out, Wt1, Wt2, Wt3);

    gemm_k<0, 2><<<256, 512, 0, stream>>>(nullptr, x, Wt1, b_in, rs, v4b, nullptr, hidden, hidout);
    gemm_k<1, 4><<<256, 512, 0, stream>>>(v4b, nullptr, Wt2, b_mid, rs, G, nullptr, hidden, hidout);
    gemm_k<2, 1><<<256, 512, 0, stream>>>(G, nullptr, Wt3, b_out, nullptr, nullptr, out, nullptr, nullptr);
}